// Round 6
// baseline (117.190 us; speedup 1.0000x reference)
//
#include <hip/hip_runtime.h>
#include <math.h>

#define MU_MAXC 32
#define MV_MAXC 32
#define OUT_UC  64
#define OUT_VC  64
#define DEG     3
#define NKNOT   (MU_MAXC + DEG + 1)   // 36
#define EPSV    1e-5f

__global__ void zero_ws_kernel(double* acc, int* bad) {
    acc[0] = 0.0; acc[1] = 0.0; acc[2] = 0.0; bad[0] = 0;
}

// Clamped open-uniform knot value, identical formula to the reference
// (padded entries k >= L-1-DEG clamp to 1.0). Branchless VALU.
__device__ __forceinline__ float kv_at(int k, int L) {
    return (k <= DEG) ? 0.f : ((k >= L - 1 - DEG) ? 1.f : (float)k / (float)(L - 1));
}

// MODE 0: per-block partials  pd[b], pd[B+b], pd[2B+b], badp[b]
// MODE 1: atomic fallback (only if ws too small)
// NOTE: no min-waves arg — a VGPR cap caused 130 MB of scratch spills in R3.
template <int MODE>
__launch_bounds__(256)
__global__ void nurbs_loss_kernel(const float* __restrict__ ctrl_pred,
                                  const float* __restrict__ ctrl_gt,
                                  const float* __restrict__ mask,
                                  const float* __restrict__ xyz,
                                  double* __restrict__ pd, int Bcnt,
                                  int* __restrict__ badp)
{
    const int b   = blockIdx.x;
    const int tid = threadIdx.x;

    __shared__ float s_tmp[OUT_UC * MV_MAXC * 3];    // 24 KB [u][j][d]
    __shared__ float s_Bu4[4 * OUT_UC];              // SoA [r][u]
    __shared__ float s_Bv4[4 * OUT_VC];              // SoA [r][v], pre-divided by sumBv
    __shared__ int   s_uoff[OUT_UC];
    __shared__ int   s_voff[OUT_VC];
    __shared__ float s_invSumBu[OUT_UC];
    __shared__ int   s_rowany[MU_MAXC];
    __shared__ int   s_colany[MV_MAXC];
    __shared__ int   s_mu, s_mv, s_bad;
    __shared__ float s_wred[4], s_wred2[4];
    __shared__ float s_ctrl_diff, s_ctrl_mask;

    if (tid < 32) { s_rowany[tid] = 0; s_colany[tid] = 0; }
    if (tid == 0) s_bad = 0;
    __syncthreads();

    // ---- Phase A (merged): masked ctrl MSE + mask sum + row/col-any flags.
    //      Thread t owns cells 4t..4t+3: 1 mask float4 + 3 pred/gt float4 pairs. ----
    float lsum_mask, lsum_diff;
    {
        const float4 mm = ((const float4*)(mask + (size_t)b * 1024))[tid];
        const float4* p4 = (const float4*)(ctrl_pred + (size_t)b * 3072);
        const float4* g4 = (const float4*)(ctrl_gt   + (size_t)b * 3072);
        const float4 pa = p4[3 * tid + 0], pb = p4[3 * tid + 1], pc = p4[3 * tid + 2];
        const float4 ga = g4[3 * tid + 0], gb = g4[3 * tid + 1], gc = g4[3 * tid + 2];
        const float a0 = pa.x - ga.x, a1 = pa.y - ga.y, a2 = pa.z - ga.z;   // cell 0
        const float b0 = pa.w - ga.w, b1 = pb.x - gb.x, b2 = pb.y - gb.y;   // cell 1
        const float c0 = pb.z - gb.z, c1 = pb.w - gb.w, c2 = pc.x - gc.x;   // cell 2
        const float e0 = pc.y - gc.y, e1 = pc.z - gc.z, e2 = pc.w - gc.w;   // cell 3
        lsum_mask = mm.x + mm.y + mm.z + mm.w;
        lsum_diff = mm.x * (a0 * a0 + a1 * a1 + a2 * a2)
                  + mm.y * (b0 * b0 + b1 * b1 + b2 * b2)
                  + mm.z * (c0 * c0 + c1 * c1 + c2 * c2)
                  + mm.w * (e0 * e0 + e1 * e1 + e2 * e2);
        const int row = tid >> 3;               // cell/32
        const int colb = (tid & 7) * 4;
        if (lsum_mask > 0.f) s_rowany[row] = 1;
        if (mm.x > 0.f) s_colany[colb + 0] = 1;
        if (mm.y > 0.f) s_colany[colb + 1] = 1;
        if (mm.z > 0.f) s_colany[colb + 2] = 1;
        if (mm.w > 0.f) s_colany[colb + 3] = 1;
    }
    #pragma unroll
    for (int off = 32; off > 0; off >>= 1) {
        lsum_mask += __shfl_down(lsum_mask, off);
        lsum_diff += __shfl_down(lsum_diff, off);
    }
    if ((tid & 63) == 0) { s_wred[tid >> 6] = lsum_mask; s_wred2[tid >> 6] = lsum_diff; }
    __syncthreads();

    if (tid == 0) {
        int cu = 0, cv = 0;
        #pragma unroll
        for (int i = 0; i < 32; i++) { cu += s_rowany[i]; cv += s_colany[i]; }
        s_mu = cu > (DEG + 1) ? cu : (DEG + 1);
        s_mv = cv > (DEG + 1) ? cv : (DEG + 1);
        s_ctrl_mask = s_wred[0] + s_wred[1] + s_wred[2] + s_wred[3];
        s_ctrl_diff = s_wred2[0] + s_wred2[1] + s_wred2[2] + s_wred2[3];
    }
    __syncthreads();

    // ---- Phase C: span-based Cox-de Boor, knots on-the-fly (no LDS, no phase B) ----
    if (tid < 128) {
        const bool isU = tid < 64;
        const int t = isU ? tid : (tid - 64);
        const int L = (isU ? s_mu : s_mv) + DEG + 1;
        const float step = (1.f - 2.f * EPSV) / 63.f;
        const float uu = (t == 63) ? (1.f - EPSV) : (EPSV + step * (float)t);

        int span = DEG;
        #pragma unroll
        for (int k = DEG + 1; k < NKNOT - 1; k++)
            if (kv_at(k, L) <= uu) span = k;

        // left[j] = uu - kv[span+1-j], right[j] = kv[span+j] - uu  (j=1..3)
        float left[DEG + 1], right[DEG + 1];
        #pragma unroll
        for (int j = 1; j <= DEG; j++) {
            left[j]  = uu - kv_at(span + 1 - j, L);
            right[j] = kv_at(span + j, L) - uu;
        }
        float N4[DEG + 1];
        N4[0] = 1.f;
        #pragma unroll
        for (int j = 1; j <= DEG; j++) {
            float saved = 0.f;
            #pragma unroll
            for (int r = 0; r < j; r++) {
                const float temp = N4[r] / (right[r + 1] + left[j - r]);
                N4[r] = saved + right[r + 1] * temp;
                saved = left[j - r] * temp;
            }
            N4[j] = saved;
        }
        const float s = N4[0] + N4[1] + N4[2] + N4[3];
        const float invs = 1.0f / s;
        const int off = span - DEG;                   // in [0, 28]
        if (isU) {
            #pragma unroll
            for (int r = 0; r < 4; r++) s_Bu4[r * 64 + t] = N4[r];
            s_uoff[t] = off; s_invSumBu[t] = invs;
        } else {
            #pragma unroll
            for (int r = 0; r < 4; r++) s_Bv4[r * 64 + t] = N4[r] * invs;  // fold 1/sumBv
            s_voff[t] = off;
        }
    }
    __syncthreads();

    // ---- Phase C2 (float4): tmp row u = sum_{r<4} Bu4[r][u] * ctrl row (uoff+r) ----
    {
        const float4* ctrl4 = (const float4*)(ctrl_pred + (size_t)b * 3072);
        float4* tmp4 = (float4*)s_tmp;
        for (int k = 0; k < 6; k++) {
            const int flat4 = tid + 256 * k;          // < 1536
            const int u = flat4 / 24;
            const int q = flat4 - u * 24;
            const int off = s_uoff[u];
            const float w0 = s_Bu4[0 * 64 + u];
            const float w1 = s_Bu4[1 * 64 + u];
            const float w2 = s_Bu4[2 * 64 + u];
            const float w3 = s_Bu4[3 * 64 + u];
            const float4 c0 = ctrl4[(off + 0) * 24 + q];
            const float4 c1 = ctrl4[(off + 1) * 24 + q];
            const float4 c2 = ctrl4[(off + 2) * 24 + q];
            const float4 c3 = ctrl4[(off + 3) * 24 + q];
            float4 a;
            a.x = w0 * c0.x + w1 * c1.x + w2 * c2.x + w3 * c3.x;
            a.y = w0 * c0.y + w1 * c1.y + w2 * c2.y + w3 * c3.y;
            a.z = w0 * c0.z + w1 * c1.z + w2 * c2.z + w3 * c3.z;
            a.w = w0 * c0.w + w1 * c1.w + w2 * c2.w + w3 * c3.w;
            tmp4[flat4] = a;
        }
    }
    __syncthreads();

    // ---- Phase D: 4 v-points per thread, xyz via 3 aligned float4 loads ----
    float lsum_surf = 0.f;
    int bad = 0;
    {
        const int vg  = (tid & 15) * 4;               // base v of this thread's group
        const int ug0 = tid >> 4;                     // 0..15
        float w[4][4]; int vo[4];
        #pragma unroll
        for (int c = 0; c < 4; c++) {
            vo[c] = s_voff[vg + c] * 3;
            #pragma unroll
            for (int r = 0; r < 4; r++) w[c][r] = s_Bv4[r * 64 + vg + c];
        }
        #pragma unroll
        for (int k = 0; k < 4; k++) {
            const int u = ug0 + 16 * k;
            const float inv = s_invSumBu[u];
            const float* tp = &s_tmp[u * 96];
            const float4* x4 = (const float4*)(xyz + ((size_t)b * 4096 + u * 64 + vg) * 3);
            const float4 xa = x4[0], xb = x4[1], xc = x4[2];
            float px[4], py[4], pz[4];
            px[0] = xa.x; py[0] = xa.y; pz[0] = xa.z;
            px[1] = xa.w; py[1] = xb.x; pz[1] = xb.y;
            px[2] = xb.z; py[2] = xb.w; pz[2] = xc.x;
            px[3] = xc.y; py[3] = xc.z; pz[3] = xc.w;
            #pragma unroll
            for (int c = 0; c < 4; c++) {
                const float* tpc = tp + vo[c];
                const float n0 = w[c][0] * tpc[0] + w[c][1] * tpc[3] + w[c][2] * tpc[6] + w[c][3] * tpc[9];
                const float n1 = w[c][0] * tpc[1] + w[c][1] * tpc[4] + w[c][2] * tpc[7] + w[c][3] * tpc[10];
                const float n2 = w[c][0] * tpc[2] + w[c][1] * tpc[5] + w[c][2] * tpc[8] + w[c][3] * tpc[11];
                const float x0 = n0 * inv, x1 = n1 * inv, x2 = n2 * inv;
                const float d0 = x0 - px[c];
                const float d1 = x1 - py[c];
                const float d2 = x2 - pz[c];
                lsum_surf += d0 * d0 + d1 * d1 + d2 * d2;
                if (!isfinite(x0) || !isfinite(x1) || !isfinite(x2)) bad = 1;
            }
        }
    }
    #pragma unroll
    for (int off = 32; off > 0; off >>= 1)
        lsum_surf += __shfl_down(lsum_surf, off);
    if ((tid & 63) == 0) s_wred[tid >> 6] = lsum_surf;
    if (bad) atomicOr(&s_bad, 1);
    __syncthreads();

    if (tid == 0) {
        const double surf = (double)s_wred[0] + s_wred[1] + s_wred[2] + s_wred[3];
        if (MODE == 0) {
            pd[b]             = (double)s_ctrl_diff;
            pd[Bcnt + b]      = (double)s_ctrl_mask;
            pd[2 * Bcnt + b]  = surf;
            badp[b]           = s_bad;
        } else {
            atomicAdd(&pd[0], (double)s_ctrl_diff);
            atomicAdd(&pd[1], (double)s_ctrl_mask);
            atomicAdd(&pd[2], surf);
            if (s_bad) atomicOr(badp, 1);
        }
    }
}

__global__ void finalize_partials_kernel(const double* __restrict__ pd,
                                         const int* __restrict__ badp,
                                         float* __restrict__ out, int Bcnt)
{
    __shared__ double sd0[4], sd1[4], sd2[4];
    __shared__ int sb[4];
    const int tid = threadIdx.x;
    double a0 = 0.0, a1 = 0.0, a2 = 0.0; int bad = 0;
    for (int i = tid; i < Bcnt; i += 256) {
        a0 += pd[i]; a1 += pd[Bcnt + i]; a2 += pd[2 * Bcnt + i];
        bad |= badp[i];
    }
    #pragma unroll
    for (int off = 32; off > 0; off >>= 1) {
        a0 += __shfl_down(a0, off);
        a1 += __shfl_down(a1, off);
        a2 += __shfl_down(a2, off);
        bad |= __shfl_down(bad, off);
    }
    if ((tid & 63) == 0) { const int w = tid >> 6; sd0[w] = a0; sd1[w] = a1; sd2[w] = a2; sb[w] = bad; }
    __syncthreads();
    if (tid == 0) {
        double d0 = 0, d1 = 0, d2 = 0; int bb = 0;
        #pragma unroll
        for (int i = 0; i < 4; i++) { d0 += sd0[i]; d1 += sd1[i]; d2 += sd2[i]; bb |= sb[i]; }
        const double denc = d1 * 3.0;
        const double lc = d0 / (denc > 1.0 ? denc : 1.0);
        const double ls = d2 / ((double)Bcnt * OUT_UC * OUT_VC * 3.0);
        out[0] = (float)(lc + ls);            // total (pre-nan-guard, per ref)
        out[1] = (float)lc;                   // loss_ctrl
        out[2] = bb ? 1.0e6f : (float)ls;     // surf_mse with nan/inf guard
    }
}

__global__ void finalize_atomic_kernel(const double* __restrict__ acc,
                                       const int* __restrict__ bad,
                                       float* __restrict__ out, int Bcnt)
{
    const double denc = acc[1] * 3.0;
    const double lc = acc[0] / (denc > 1.0 ? denc : 1.0);
    const double ls = acc[2] / ((double)Bcnt * OUT_UC * OUT_VC * 3.0);
    out[0] = (float)(lc + ls);
    out[1] = (float)lc;
    out[2] = bad[0] ? 1.0e6f : (float)ls;
}

extern "C" void kernel_launch(void* const* d_in, const int* in_sizes, int n_in,
                              void* d_out, int out_size, void* d_ws, size_t ws_size,
                              hipStream_t stream)
{
    const float* pred = (const float*)d_in[0];
    const float* gt   = (const float*)d_in[1];
    const float* mask = (const float*)d_in[2];
    const float* xyz  = (const float*)d_in[3];
    const int Bcnt = in_sizes[2] / (MU_MAXC * MV_MAXC);   // 1024

    double* pd = (double*)d_ws;
    float* out = (float*)d_out;

    const size_t need = (size_t)3 * Bcnt * sizeof(double) + (size_t)Bcnt * sizeof(int);
    if (ws_size >= need) {
        int* badp = (int*)(pd + 3 * Bcnt);
        hipLaunchKernelGGL((nurbs_loss_kernel<0>), dim3(Bcnt), dim3(256), 0, stream,
                           pred, gt, mask, xyz, pd, Bcnt, badp);
        hipLaunchKernelGGL(finalize_partials_kernel, dim3(1), dim3(256), 0, stream,
                           pd, badp, out, Bcnt);
    } else {
        int* badp = (int*)(pd + 3);
        hipLaunchKernelGGL(zero_ws_kernel, dim3(1), dim3(1), 0, stream, pd, badp);
        hipLaunchKernelGGL((nurbs_loss_kernel<1>), dim3(Bcnt), dim3(256), 0, stream,
                           pred, gt, mask, xyz, pd, Bcnt, badp);
        hipLaunchKernelGGL(finalize_atomic_kernel, dim3(1), dim3(1), 0, stream,
                           pd, badp, out, Bcnt);
    }
}

// Round 7
// 115.195 us; speedup vs baseline: 1.0173x; 1.0173x over previous
//
#include <hip/hip_runtime.h>
#include <math.h>

#define MU_MAXC 32
#define MV_MAXC 32
#define OUT_UC  64
#define OUT_VC  64
#define DEG     3
#define NKNOT   (MU_MAXC + DEG + 1)   // 36
#define EPSV    1e-5f

__global__ void zero_ws_kernel(double* acc, int* bad) {
    acc[0] = 0.0; acc[1] = 0.0; acc[2] = 0.0; bad[0] = 0;
}

// Clamped open-uniform knot value (padded k >= L-1-DEG clamps to 1.0).
__device__ __forceinline__ float kv_at(int k, int L) {
    return (k <= DEG) ? 0.f : ((k >= L - 1 - DEG) ? 1.f : (float)k / (float)(L - 1));
}

// Half-sample blocks: grid = 2*Bcnt, block bb handles sample s=bb>>1,
// u-rows [32h, 32h+32) where h=bb&1.  ~15 KB LDS -> LDS never caps occupancy;
// 2x blocks pipeline phase-A (global-latency) of one generation against
// phase-D (LDS) of the previous, breaking single-round lockstep.
// MODE 0: per-block partials; MODE 1: atomic fallback.
// NOTE: no min-waves arg — a VGPR cap caused 130 MB of scratch spills in R3.
template <int MODE>
__launch_bounds__(256)
__global__ void nurbs_loss_kernel(const float* __restrict__ ctrl_pred,
                                  const float* __restrict__ ctrl_gt,
                                  const float* __restrict__ mask,
                                  const float* __restrict__ xyz,
                                  double* __restrict__ pd, int G,
                                  int* __restrict__ badp)
{
    const int bb  = blockIdx.x;
    const int s   = bb >> 1;            // sample
    const int h   = bb & 1;             // u-half
    const int tid = threadIdx.x;

    __shared__ float s_tmp[32 * MV_MAXC * 3];        // 12 KB [lu][j][d], lu=local u
    __shared__ float s_Bu4[4 * 32];                  // SoA [r][lu]
    __shared__ float s_Bv4[4 * OUT_VC];              // SoA [r][v], pre-divided by sumBv
    __shared__ int   s_uoff[32];
    __shared__ int   s_voff[OUT_VC];
    __shared__ float s_invSumBu[32];
    __shared__ int   s_rowany[MU_MAXC];
    __shared__ int   s_colany[MV_MAXC];
    __shared__ int   s_mu, s_mv, s_bad;
    __shared__ float s_wred[4], s_wred2[4];
    __shared__ float s_ctrl_diff, s_ctrl_mask;

    if (tid < 32) { s_rowany[tid] = 0; s_colany[tid] = 0; }
    if (tid == 0) s_bad = 0;
    __syncthreads();

    // ---- Phase A: full-sample mask scan (mu/mv) + HALF-sample masked ctrl MSE.
    //      Thread t owns mask cells 4t..4t+3; threads [128h,128h+128) own the
    //      MSE for cells [512h, 512h+512) (4 cells each). ----
    float lsum_mask, lsum_diff = 0.f;
    float4 mm;
    {
        mm = ((const float4*)(mask + (size_t)s * 1024))[tid];
        lsum_mask = mm.x + mm.y + mm.z + mm.w;
        const int row = tid >> 3;
        const int colb = (tid & 7) * 4;
        if (lsum_mask > 0.f) s_rowany[row] = 1;
        if (mm.x > 0.f) s_colany[colb + 0] = 1;
        if (mm.y > 0.f) s_colany[colb + 1] = 1;
        if (mm.z > 0.f) s_colany[colb + 2] = 1;
        if (mm.w > 0.f) s_colany[colb + 3] = 1;
    }
    if ((tid >> 7) == h) {              // this thread's 4 cells lie in our half
        const float4* p4 = (const float4*)(ctrl_pred + (size_t)s * 3072);
        const float4* g4 = (const float4*)(ctrl_gt   + (size_t)s * 3072);
        const float4 pa = p4[3 * tid + 0], pb = p4[3 * tid + 1], pc = p4[3 * tid + 2];
        const float4 ga = g4[3 * tid + 0], gb = g4[3 * tid + 1], gc = g4[3 * tid + 2];
        const float a0 = pa.x - ga.x, a1 = pa.y - ga.y, a2 = pa.z - ga.z;   // cell 0
        const float b0 = pa.w - ga.w, b1 = pb.x - gb.x, b2 = pb.y - gb.y;   // cell 1
        const float c0 = pb.z - gb.z, c1 = pb.w - gb.w, c2 = pc.x - gc.x;   // cell 2
        const float e0 = pc.y - gc.y, e1 = pc.z - gc.z, e2 = pc.w - gc.w;   // cell 3
        lsum_diff = mm.x * (a0 * a0 + a1 * a1 + a2 * a2)
                  + mm.y * (b0 * b0 + b1 * b1 + b2 * b2)
                  + mm.z * (c0 * c0 + c1 * c1 + c2 * c2)
                  + mm.w * (e0 * e0 + e1 * e1 + e2 * e2);
    }
    // half of the full-sample mask sum so the two sibling blocks sum to 1x
    lsum_mask *= 0.5f;
    #pragma unroll
    for (int off = 32; off > 0; off >>= 1) {
        lsum_mask += __shfl_down(lsum_mask, off);
        lsum_diff += __shfl_down(lsum_diff, off);
    }
    if ((tid & 63) == 0) { s_wred[tid >> 6] = lsum_mask; s_wred2[tid >> 6] = lsum_diff; }
    __syncthreads();

    if (tid == 0) {
        int cu = 0, cv = 0;
        #pragma unroll
        for (int i = 0; i < 32; i++) { cu += s_rowany[i]; cv += s_colany[i]; }
        s_mu = cu > (DEG + 1) ? cu : (DEG + 1);
        s_mv = cv > (DEG + 1) ? cv : (DEG + 1);
        s_ctrl_mask = s_wred[0] + s_wred[1] + s_wred[2] + s_wred[3];
        s_ctrl_diff = s_wred2[0] + s_wred2[1] + s_wred2[2] + s_wred2[3];
    }
    __syncthreads();

    // ---- Phase C: span-based Cox-de Boor, knots on-the-fly.
    //      threads 0..63: v-basis (all v); threads 64..95: u-basis for our 32 u's ----
    if (tid < 96) {
        const bool isV = tid < 64;
        const int t = isV ? tid : (tid - 64);          // v, or local u
        const int gidx = isV ? t : (32 * h + t);       // global grid index
        const int L = (isV ? s_mv : s_mu) + DEG + 1;
        const float step = (1.f - 2.f * EPSV) / 63.f;
        const float uu = (gidx == 63) ? (1.f - EPSV) : (EPSV + step * (float)gidx);

        int span = DEG;
        #pragma unroll
        for (int k = DEG + 1; k < NKNOT - 1; k++)
            if (kv_at(k, L) <= uu) span = k;

        float left[DEG + 1], right[DEG + 1];
        #pragma unroll
        for (int j = 1; j <= DEG; j++) {
            left[j]  = uu - kv_at(span + 1 - j, L);
            right[j] = kv_at(span + j, L) - uu;
        }
        float N4[DEG + 1];
        N4[0] = 1.f;
        #pragma unroll
        for (int j = 1; j <= DEG; j++) {
            float saved = 0.f;
            #pragma unroll
            for (int r = 0; r < j; r++) {
                const float temp = N4[r] / (right[r + 1] + left[j - r]);
                N4[r] = saved + right[r + 1] * temp;
                saved = left[j - r] * temp;
            }
            N4[j] = saved;
        }
        const float sum = N4[0] + N4[1] + N4[2] + N4[3];
        const float invs = 1.0f / sum;
        const int off = span - DEG;                   // in [0, 28]
        if (isV) {
            #pragma unroll
            for (int r = 0; r < 4; r++) s_Bv4[r * 64 + t] = N4[r] * invs;  // fold 1/sumBv
            s_voff[t] = off;
        } else {
            #pragma unroll
            for (int r = 0; r < 4; r++) s_Bu4[r * 32 + t] = N4[r];
            s_uoff[t] = off; s_invSumBu[t] = invs;
        }
    }
    __syncthreads();

    // ---- Phase C2 (float4): tmp row lu = sum_{r<4} Bu4[r][lu] * ctrl row (uoff+r)
    //      768 float4s / 256 threads = 3 each ----
    {
        const float4* ctrl4 = (const float4*)(ctrl_pred + (size_t)s * 3072);
        float4* tmp4 = (float4*)s_tmp;
        #pragma unroll
        for (int k = 0; k < 3; k++) {
            const int flat4 = tid + 256 * k;          // < 768
            const int lu = flat4 / 24;
            const int q = flat4 - lu * 24;
            const int off = s_uoff[lu];
            const float w0 = s_Bu4[0 * 32 + lu];
            const float w1 = s_Bu4[1 * 32 + lu];
            const float w2 = s_Bu4[2 * 32 + lu];
            const float w3 = s_Bu4[3 * 32 + lu];
            const float4 c0 = ctrl4[(off + 0) * 24 + q];
            const float4 c1 = ctrl4[(off + 1) * 24 + q];
            const float4 c2 = ctrl4[(off + 2) * 24 + q];
            const float4 c3 = ctrl4[(off + 3) * 24 + q];
            float4 a;
            a.x = w0 * c0.x + w1 * c1.x + w2 * c2.x + w3 * c3.x;
            a.y = w0 * c0.y + w1 * c1.y + w2 * c2.y + w3 * c3.y;
            a.z = w0 * c0.z + w1 * c1.z + w2 * c2.z + w3 * c3.z;
            a.w = w0 * c0.w + w1 * c1.w + w2 * c2.w + w3 * c3.w;
            tmp4[flat4] = a;
        }
    }
    __syncthreads();

    // ---- Phase D: 2048 points (32 u x 64 v) / 256 thr = 8 per thread.
    //      4 consecutive v per thread; xyz via 3 aligned float4 loads ----
    float lsum_surf = 0.f;
    int bad = 0;
    {
        const int vg   = (tid & 15) * 4;
        const int lug0 = tid >> 4;                    // 0..15
        float w[4][4]; int vo[4];
        #pragma unroll
        for (int c = 0; c < 4; c++) {
            vo[c] = s_voff[vg + c] * 3;
            #pragma unroll
            for (int r = 0; r < 4; r++) w[c][r] = s_Bv4[r * 64 + vg + c];
        }
        #pragma unroll
        for (int k = 0; k < 2; k++) {
            const int lu = lug0 + 16 * k;
            const int u  = 32 * h + lu;
            const float inv = s_invSumBu[lu];
            const float* tp = &s_tmp[lu * 96];
            const float4* x4 = (const float4*)(xyz + ((size_t)s * 4096 + u * 64 + vg) * 3);
            const float4 xa = x4[0], xb = x4[1], xc = x4[2];
            float px[4], py[4], pz[4];
            px[0] = xa.x; py[0] = xa.y; pz[0] = xa.z;
            px[1] = xa.w; py[1] = xb.x; pz[1] = xb.y;
            px[2] = xb.z; py[2] = xb.w; pz[2] = xc.x;
            px[3] = xc.y; py[3] = xc.z; pz[3] = xc.w;
            #pragma unroll
            for (int c = 0; c < 4; c++) {
                const float* tpc = tp + vo[c];
                const float n0 = w[c][0] * tpc[0] + w[c][1] * tpc[3] + w[c][2] * tpc[6] + w[c][3] * tpc[9];
                const float n1 = w[c][0] * tpc[1] + w[c][1] * tpc[4] + w[c][2] * tpc[7] + w[c][3] * tpc[10];
                const float n2 = w[c][0] * tpc[2] + w[c][1] * tpc[5] + w[c][2] * tpc[8] + w[c][3] * tpc[11];
                const float x0 = n0 * inv, x1 = n1 * inv, x2 = n2 * inv;
                const float d0 = x0 - px[c];
                const float d1 = x1 - py[c];
                const float d2 = x2 - pz[c];
                lsum_surf += d0 * d0 + d1 * d1 + d2 * d2;
                if (!isfinite(x0) || !isfinite(x1) || !isfinite(x2)) bad = 1;
            }
        }
    }
    #pragma unroll
    for (int off = 32; off > 0; off >>= 1)
        lsum_surf += __shfl_down(lsum_surf, off);
    if ((tid & 63) == 0) s_wred[tid >> 6] = lsum_surf;
    if (bad) atomicOr(&s_bad, 1);
    __syncthreads();

    if (tid == 0) {
        const double surf = (double)s_wred[0] + s_wred[1] + s_wred[2] + s_wred[3];
        if (MODE == 0) {
            pd[bb]          = (double)s_ctrl_diff;
            pd[G + bb]      = (double)s_ctrl_mask;
            pd[2 * G + bb]  = surf;
            badp[bb]        = s_bad;
        } else {
            atomicAdd(&pd[0], (double)s_ctrl_diff);
            atomicAdd(&pd[1], (double)s_ctrl_mask);
            atomicAdd(&pd[2], surf);
            if (s_bad) atomicOr(badp, 1);
        }
    }
}

__global__ void finalize_partials_kernel(const double* __restrict__ pd,
                                         const int* __restrict__ badp,
                                         float* __restrict__ out, int G, int Bcnt)
{
    __shared__ double sd0[4], sd1[4], sd2[4];
    __shared__ int sb[4];
    const int tid = threadIdx.x;
    double a0 = 0.0, a1 = 0.0, a2 = 0.0; int bad = 0;
    for (int i = tid; i < G; i += 256) {
        a0 += pd[i]; a1 += pd[G + i]; a2 += pd[2 * G + i];
        bad |= badp[i];
    }
    #pragma unroll
    for (int off = 32; off > 0; off >>= 1) {
        a0 += __shfl_down(a0, off);
        a1 += __shfl_down(a1, off);
        a2 += __shfl_down(a2, off);
        bad |= __shfl_down(bad, off);
    }
    if ((tid & 63) == 0) { const int w = tid >> 6; sd0[w] = a0; sd1[w] = a1; sd2[w] = a2; sb[w] = bad; }
    __syncthreads();
    if (tid == 0) {
        double d0 = 0, d1 = 0, d2 = 0; int bb = 0;
        #pragma unroll
        for (int i = 0; i < 4; i++) { d0 += sd0[i]; d1 += sd1[i]; d2 += sd2[i]; bb |= sb[i]; }
        const double denc = d1 * 3.0;
        const double lc = d0 / (denc > 1.0 ? denc : 1.0);
        const double ls = d2 / ((double)Bcnt * OUT_UC * OUT_VC * 3.0);
        out[0] = (float)(lc + ls);            // total (pre-nan-guard, per ref)
        out[1] = (float)lc;                   // loss_ctrl
        out[2] = bb ? 1.0e6f : (float)ls;     // surf_mse with nan/inf guard
    }
}

__global__ void finalize_atomic_kernel(const double* __restrict__ acc,
                                       const int* __restrict__ bad,
                                       float* __restrict__ out, int Bcnt)
{
    const double denc = acc[1] * 3.0;
    const double lc = acc[0] / (denc > 1.0 ? denc : 1.0);
    const double ls = acc[2] / ((double)Bcnt * OUT_UC * OUT_VC * 3.0);
    out[0] = (float)(lc + ls);
    out[1] = (float)lc;
    out[2] = bad[0] ? 1.0e6f : (float)ls;
}

extern "C" void kernel_launch(void* const* d_in, const int* in_sizes, int n_in,
                              void* d_out, int out_size, void* d_ws, size_t ws_size,
                              hipStream_t stream)
{
    const float* pred = (const float*)d_in[0];
    const float* gt   = (const float*)d_in[1];
    const float* mask = (const float*)d_in[2];
    const float* xyz  = (const float*)d_in[3];
    const int Bcnt = in_sizes[2] / (MU_MAXC * MV_MAXC);   // 1024
    const int G = 2 * Bcnt;                               // half-sample blocks

    double* pd = (double*)d_ws;
    float* out = (float*)d_out;

    const size_t need = (size_t)3 * G * sizeof(double) + (size_t)G * sizeof(int);
    if (ws_size >= need) {
        int* badp = (int*)(pd + 3 * G);
        hipLaunchKernelGGL((nurbs_loss_kernel<0>), dim3(G), dim3(256), 0, stream,
                           pred, gt, mask, xyz, pd, G, badp);
        hipLaunchKernelGGL(finalize_partials_kernel, dim3(1), dim3(256), 0, stream,
                           pd, badp, out, G, Bcnt);
    } else {
        int* badp = (int*)(pd + 3);
        hipLaunchKernelGGL(zero_ws_kernel, dim3(1), dim3(1), 0, stream, pd, badp);
        hipLaunchKernelGGL((nurbs_loss_kernel<1>), dim3(G), dim3(256), 0, stream,
                           pred, gt, mask, xyz, pd, G, badp);
        hipLaunchKernelGGL(finalize_atomic_kernel, dim3(1), dim3(1), 0, stream,
                           pd, badp, out, Bcnt);
    }
}